// Round 1
// baseline (2095.251 us; speedup 1.0000x reference)
//
#include <hip/hip_runtime.h>
#include <math.h>

// Problem constants (from reference): B=4, T=2048, C=768, H=12, D=64
#define BATCH   4
#define TSEQ    2048
#define CEMB    768
#define NHEAD   12
#define HDIM    64
#define BTROWS  (BATCH * TSEQ)      // 8192
#define QKVCOLS (3 * CEMB)          // 2304

// ---------------------------------------------------------------------------
// GEMM: C[M][N] = A[M][K] @ B[K][N] + bias[N]   (fp32, vector ALU)
// BM=BN=128, BK=16, 256 threads, 8x8 micro-tile per thread.
// M=8192, K=768, N in {2304, 768} -- all exactly divisible, no bounds checks.
// ---------------------------------------------------------------------------
template <int BM, int BN, int BK>
__global__ __launch_bounds__(256)
void gemm_bias_kernel(const float* __restrict__ A, const float* __restrict__ B,
                      const float* __restrict__ bias, float* __restrict__ C,
                      int M, int N, int K) {
    __shared__ float As[BK][BM];   // transposed A tile: As[k][m]
    __shared__ float Bs[BK][BN];

    const int tid = threadIdx.x;
    const int ntx = N / BN;
    const int bx  = blockIdx.x % ntx;   // col tile
    const int by  = blockIdx.x / ntx;   // row tile
    const int m0  = by * BM;
    const int n0  = bx * BN;
    const int tx  = tid & 15;           // 16 col-threads
    const int ty  = tid >> 4;           // 16 row-threads

    float acc[8][8] = {};

    for (int k0 = 0; k0 < K; k0 += BK) {
        // --- stage A tile (BM x BK = 128x16 floats = 512 float4; 2/thread)
#pragma unroll
        for (int i = 0; i < 2; ++i) {
            int li  = tid + i * 256;
            int row = li >> 2;          // 0..127
            int cc  = li & 3;           // float4 index along K
            float4 v = *reinterpret_cast<const float4*>(
                &A[(size_t)(m0 + row) * K + k0 + cc * 4]);
            As[cc * 4 + 0][row] = v.x;
            As[cc * 4 + 1][row] = v.y;
            As[cc * 4 + 2][row] = v.z;
            As[cc * 4 + 3][row] = v.w;
        }
        // --- stage B tile (BK x BN = 16x128 = 512 float4; 2/thread)
#pragma unroll
        for (int i = 0; i < 2; ++i) {
            int li  = tid + i * 256;
            int row = li >> 5;          // 0..15
            int cc  = li & 31;          // float4 index along N
            *reinterpret_cast<float4*>(&Bs[row][cc * 4]) =
                *reinterpret_cast<const float4*>(
                    &B[(size_t)(k0 + row) * N + n0 + cc * 4]);
        }
        __syncthreads();

#pragma unroll
        for (int k = 0; k < BK; ++k) {
            float a[8], b[8];
            *reinterpret_cast<float4*>(&a[0]) =
                *reinterpret_cast<const float4*>(&As[k][ty * 8 + 0]);
            *reinterpret_cast<float4*>(&a[4]) =
                *reinterpret_cast<const float4*>(&As[k][ty * 8 + 4]);
            *reinterpret_cast<float4*>(&b[0]) =
                *reinterpret_cast<const float4*>(&Bs[k][tx * 8 + 0]);
            *reinterpret_cast<float4*>(&b[4]) =
                *reinterpret_cast<const float4*>(&Bs[k][tx * 8 + 4]);
#pragma unroll
            for (int i = 0; i < 8; ++i)
#pragma unroll
                for (int j = 0; j < 8; ++j)
                    acc[i][j] += a[i] * b[j];
        }
        __syncthreads();
    }

    // --- epilogue: add bias, coalesced float4 stores
#pragma unroll
    for (int i = 0; i < 8; ++i) {
        int row = m0 + ty * 8 + i;
#pragma unroll
        for (int j = 0; j < 8; j += 4) {
            int col = n0 + tx * 8 + j;
            float4 v;
            v.x = acc[i][j + 0] + bias[col + 0];
            v.y = acc[i][j + 1] + bias[col + 1];
            v.z = acc[i][j + 2] + bias[col + 2];
            v.w = acc[i][j + 3] + bias[col + 3];
            *reinterpret_cast<float4*>(&C[(size_t)row * N + col]) = v;
        }
    }
}

// ---------------------------------------------------------------------------
// Causal flash attention, fp32 online softmax.
// qkv layout: [BT][2304] with q at col h*64, k at 768+h*64, v at 1536+h*64.
// Grid: B*H*(T/64) blocks of 256 threads. Each block: one (b,h) 64-row Q tile.
// Thread (r, c4): r = tid>>2 (q row in tile), c4 = tid&3.
//   - owns S/P columns j == jj*4 + c4 (16 of 64)
//   - accumulates O[r][c4*16 .. c4*16+15]
// K rows j=jj*4+c4 at row-pad 72 -> banks 8*c4 = {0,8,16,24}: conflict-free.
// ---------------------------------------------------------------------------
__global__ __launch_bounds__(256)
void attn_kernel(const float* __restrict__ qkv, float* __restrict__ y) {
    constexpr int QB = 64, KB = 64, PAD = 72;
    __shared__ float Qs[QB][PAD];
    __shared__ float Ks[KB][PAD];
    __shared__ float Vs[KB][PAD];

    const int tid = threadIdx.x;
    const int bid = blockIdx.x;
    const int nqt = TSEQ / QB;            // 32
    const int qt  = bid % nqt;
    const int bh  = bid / nqt;
    const int h   = bh % NHEAD;
    const int b   = bh / NHEAD;
    const int q0  = qt * QB;
    const size_t rowbase = (size_t)b * TSEQ;

    // --- stage Q tile (scaled by 1/sqrt(D) = 0.125 exactly)
#pragma unroll
    for (int i = 0; i < 4; ++i) {
        int li = tid + i * 256;
        int r  = li >> 4;                 // 0..63
        int c  = li & 15;                 // float4 along D
        float4 v = *reinterpret_cast<const float4*>(
            &qkv[(rowbase + q0 + r) * QKVCOLS + h * HDIM + c * 4]);
        v.x *= 0.125f; v.y *= 0.125f; v.z *= 0.125f; v.w *= 0.125f;
        *reinterpret_cast<float4*>(&Qs[r][c * 4]) = v;
    }
    __syncthreads();

    const int r  = tid >> 2;
    const int c4 = tid & 3;
    const int q  = q0 + r;
    const int base_lane = (tid & 63) & ~3;

    // Q row into registers (64 floats)
    float qr[64];
#pragma unroll
    for (int i = 0; i < 16; ++i)
        *reinterpret_cast<float4*>(&qr[i * 4]) =
            *reinterpret_cast<const float4*>(&Qs[r][i * 4]);

    float o[16] = {};
    float m = -INFINITY;
    float l = 0.0f;

    for (int kt = 0; kt <= qt; ++kt) {
        __syncthreads();   // protect Ks/Vs from overwrite while in use
        // --- stage K and V tiles
#pragma unroll
        for (int i = 0; i < 4; ++i) {
            int li = tid + i * 256;
            int rr = li >> 4;
            int cc = li & 15;
            size_t grow = (rowbase + kt * KB + rr) * QKVCOLS + h * HDIM + cc * 4;
            *reinterpret_cast<float4*>(&Ks[rr][cc * 4]) =
                *reinterpret_cast<const float4*>(&qkv[grow + CEMB]);
            *reinterpret_cast<float4*>(&Vs[rr][cc * 4]) =
                *reinterpret_cast<const float4*>(&qkv[grow + 2 * CEMB]);
        }
        __syncthreads();

        // --- S = (Q*scale) K^T for this thread's 16 columns
        float p[16];
        float mloc = -INFINITY;
#pragma unroll
        for (int jj = 0; jj < 16; ++jj) {
            int j = jj * 4 + c4;
            float s = 0.0f;
#pragma unroll
            for (int d = 0; d < 64; d += 4) {
                float4 kv = *reinterpret_cast<const float4*>(&Ks[j][d]);
                s += qr[d + 0] * kv.x + qr[d + 1] * kv.y +
                     qr[d + 2] * kv.z + qr[d + 3] * kv.w;
            }
            int jg = kt * KB + j;
            s = (jg <= q) ? s : -INFINITY;   // causal mask
            p[jj] = s;
            mloc = fmaxf(mloc, s);
        }
        // quad (4 threads/row) max reduce
        mloc = fmaxf(mloc, __shfl_xor(mloc, 1));
        mloc = fmaxf(mloc, __shfl_xor(mloc, 2));
        float mnew  = fmaxf(m, mloc);
        float scale = __expf(m - mnew);      // exp(-inf) = 0 on first tile

        float psum = 0.0f;
#pragma unroll
        for (int jj = 0; jj < 16; ++jj) {
            p[jj] = __expf(p[jj] - mnew);
            psum += p[jj];
        }
        psum += __shfl_xor(psum, 1);
        psum += __shfl_xor(psum, 2);
        l = l * scale + psum;
        m = mnew;
#pragma unroll
        for (int i = 0; i < 16; ++i) o[i] *= scale;

        // --- O += P V  (shuffle-broadcast P across the quad)
#pragma unroll
        for (int jj = 0; jj < 16; ++jj) {
#pragma unroll
            for (int cc2 = 0; cc2 < 4; ++cc2) {
                float pj = __shfl(p[jj], base_lane + cc2);
                int j = jj * 4 + cc2;
#pragma unroll
                for (int i = 0; i < 4; ++i) {
                    float4 vv = *reinterpret_cast<const float4*>(
                        &Vs[j][c4 * 16 + i * 4]);
                    o[i * 4 + 0] += pj * vv.x;
                    o[i * 4 + 1] += pj * vv.y;
                    o[i * 4 + 2] += pj * vv.z;
                    o[i * 4 + 3] += pj * vv.w;
                }
            }
        }
    }

    const float inv = 1.0f / l;
#pragma unroll
    for (int i = 0; i < 4; ++i) {
        float4 v;
        v.x = o[i * 4 + 0] * inv;
        v.y = o[i * 4 + 1] * inv;
        v.z = o[i * 4 + 2] * inv;
        v.w = o[i * 4 + 3] * inv;
        *reinterpret_cast<float4*>(
            &y[(rowbase + q0 + r) * CEMB + h * HDIM + c4 * 16 + i * 4]) = v;
    }
}

// ---------------------------------------------------------------------------
extern "C" void kernel_launch(void* const* d_in, const int* in_sizes, int n_in,
                              void* d_out, int out_size, void* d_ws, size_t ws_size,
                              hipStream_t stream) {
    const float* x     = (const float*)d_in[0];
    const float* Wqkv  = (const float*)d_in[1];
    const float* bqkv  = (const float*)d_in[2];
    const float* Wproj = (const float*)d_in[3];
    const float* bproj = (const float*)d_in[4];
    float* out = (float*)d_out;

    // workspace: qkv [8192][2304] fp32 (75.5 MB), then y [8192][768] fp32 (25 MB)
    float* qkv = (float*)d_ws;
    float* yb  = (float*)((char*)d_ws + (size_t)BTROWS * QKVCOLS * sizeof(float));

    // 1) qkv = x @ Wqkv + bqkv
    {
        dim3 grid((BTROWS / 128) * (QKVCOLS / 128));   // 64*18 = 1152
        gemm_bias_kernel<128, 128, 16><<<grid, 256, 0, stream>>>(
            x, Wqkv, bqkv, qkv, BTROWS, QKVCOLS, CEMB);
    }
    // 2) causal attention -> y [BT][768]
    {
        dim3 grid(BATCH * NHEAD * (TSEQ / 64));        // 1536
        attn_kernel<<<grid, 256, 0, stream>>>(qkv, yb);
    }
    // 3) out = y @ Wproj + bproj
    {
        dim3 grid((BTROWS / 128) * (CEMB / 128));      // 64*6 = 384
        gemm_bias_kernel<128, 128, 16><<<grid, 256, 0, stream>>>(
            yb, Wproj, bproj, out, BTROWS, CEMB, CEMB);
    }
}

// Round 2
// 790.738 us; speedup vs baseline: 2.6497x; 2.6497x over previous
//
#include <hip/hip_runtime.h>
#include <math.h>

// Problem constants: B=4, T=2048, C=768, H=12, D=64
#define BATCH   4
#define TSEQ    2048
#define CEMB    768
#define NHEAD   12
#define HDIM    64
#define BTROWS  (BATCH * TSEQ)      // 8192
#define QKVCOLS (3 * CEMB)          // 2304

typedef _Float16 half8  __attribute__((ext_vector_type(8)));
typedef _Float16 half2v __attribute__((ext_vector_type(2)));
typedef float    f32x4  __attribute__((ext_vector_type(4)));

// ---------------------------------------------------------------------------
// GEMM: unchanged from round 1 (passed; ~490us combined). Next target.
// ---------------------------------------------------------------------------
template <int BM, int BN, int BK>
__global__ __launch_bounds__(256)
void gemm_bias_kernel(const float* __restrict__ A, const float* __restrict__ B,
                      const float* __restrict__ bias, float* __restrict__ C,
                      int M, int N, int K) {
    __shared__ float As[BK][BM];
    __shared__ float Bs[BK][BN];

    const int tid = threadIdx.x;
    const int ntx = N / BN;
    const int bx  = blockIdx.x % ntx;
    const int by  = blockIdx.x / ntx;
    const int m0  = by * BM;
    const int n0  = bx * BN;
    const int tx  = tid & 15;
    const int ty  = tid >> 4;

    float acc[8][8] = {};

    for (int k0 = 0; k0 < K; k0 += BK) {
#pragma unroll
        for (int i = 0; i < 2; ++i) {
            int li  = tid + i * 256;
            int row = li >> 2;
            int cc  = li & 3;
            float4 v = *reinterpret_cast<const float4*>(
                &A[(size_t)(m0 + row) * K + k0 + cc * 4]);
            As[cc * 4 + 0][row] = v.x;
            As[cc * 4 + 1][row] = v.y;
            As[cc * 4 + 2][row] = v.z;
            As[cc * 4 + 3][row] = v.w;
        }
#pragma unroll
        for (int i = 0; i < 2; ++i) {
            int li  = tid + i * 256;
            int row = li >> 5;
            int cc  = li & 31;
            *reinterpret_cast<float4*>(&Bs[row][cc * 4]) =
                *reinterpret_cast<const float4*>(
                    &B[(size_t)(k0 + row) * N + n0 + cc * 4]);
        }
        __syncthreads();

#pragma unroll
        for (int k = 0; k < BK; ++k) {
            float a[8], b[8];
            *reinterpret_cast<float4*>(&a[0]) =
                *reinterpret_cast<const float4*>(&As[k][ty * 8 + 0]);
            *reinterpret_cast<float4*>(&a[4]) =
                *reinterpret_cast<const float4*>(&As[k][ty * 8 + 4]);
            *reinterpret_cast<float4*>(&b[0]) =
                *reinterpret_cast<const float4*>(&Bs[k][tx * 8 + 0]);
            *reinterpret_cast<float4*>(&b[4]) =
                *reinterpret_cast<const float4*>(&Bs[k][tx * 8 + 4]);
#pragma unroll
            for (int i = 0; i < 8; ++i)
#pragma unroll
                for (int j = 0; j < 8; ++j)
                    acc[i][j] += a[i] * b[j];
        }
        __syncthreads();
    }

#pragma unroll
    for (int i = 0; i < 8; ++i) {
        int row = m0 + ty * 8 + i;
#pragma unroll
        for (int j = 0; j < 8; j += 4) {
            int col = n0 + tx * 8 + j;
            float4 v;
            v.x = acc[i][j + 0] + bias[col + 0];
            v.y = acc[i][j + 1] + bias[col + 1];
            v.z = acc[i][j + 2] + bias[col + 2];
            v.w = acc[i][j + 3] + bias[col + 3];
            *reinterpret_cast<float4*>(&C[(size_t)row * N + col]) = v;
        }
    }
}

// ---------------------------------------------------------------------------
// Flash attention with f16 MFMA (fp32 accumulate + fp32 online softmax).
// Block = 256 threads = 4 waves; Q tile 64 rows (wave w owns rows w*16..+15).
// mfma_f32_16x16x32_f16 layouts (guide-verified C/D, standard A/B):
//   A: lane l holds A[l&15][(l>>4)*8 + i]      (8 contiguous k)
//   B: lane l holds B[(l>>4)*8 + i][l&15]
//   D: lane l, reg r holds D[(l>>4)*4 + r][l&15]
// QK^T: A=Q (k-dim=d), B=K^T -> lane reads K row (l&15), contiguous d.   OK
// PV:   A=P (k-dim=k),  B=V  -> lane needs V column -> stage V transposed.
// K in LDS [64][72] f16 (144B rows, bank-spread). Vt XOR-swizzled 16B blocks.
// P round-trips through per-wave-private LDS (same-wave lgkmcnt ordering).
// LDS total 26.6KB -> 4+ blocks/CU (was 55KB -> 2).
// ---------------------------------------------------------------------------
__global__ __launch_bounds__(256)
void attn_kernel(const float* __restrict__ qkv, float* __restrict__ y) {
    __shared__ _Float16 Kls[64][72];        // 9216 B
    __shared__ _Float16 Vt[64 * 64];        // 8192 B, swizzled: Vt[d][k]
    __shared__ _Float16 Pls[4][16][72];     // 9216 B, per-wave private

    const int tid = threadIdx.x;
    const int w   = tid >> 6;        // wave 0..3
    const int l   = tid & 63;
    const int lj  = l & 15;          // fragment "row/col" lane index
    const int lg  = l >> 4;          // lane group 0..3

    const int qt = blockIdx.x & 31;          // q tile 0..31
    const int bh = blockIdx.x >> 5;
    const int h  = bh % NHEAD;
    const int b  = bh / NHEAD;
    const int q0 = qt * 64;
    const size_t rowbase = (size_t)b * TSEQ;

    // --- Q fragments to registers (scaled by 1/8), once per block
    half8 qf[2];
    {
        const float* qrow =
            qkv + (rowbase + q0 + w * 16 + lj) * QKVCOLS + h * HDIM;
#pragma unroll
        for (int kc = 0; kc < 2; ++kc) {
            const float* p = qrow + kc * 32 + lg * 8;
            float4 a = *reinterpret_cast<const float4*>(p);
            float4 c = *reinterpret_cast<const float4*>(p + 4);
            float f[8] = {a.x, a.y, a.z, a.w, c.x, c.y, c.z, c.w};
            half8 hv;
#pragma unroll
            for (int i = 0; i < 8; ++i) hv[i] = (_Float16)(f[i] * 0.125f);
            qf[kc] = hv;
        }
    }

    f32x4 O[4];
#pragma unroll
    for (int dt = 0; dt < 4; ++dt) O[dt] = (f32x4){0.f, 0.f, 0.f, 0.f};
    float mrow[4] = {-INFINITY, -INFINITY, -INFINITY, -INFINITY};
    float lrow[4] = {0.f, 0.f, 0.f, 0.f};

    for (int kt = 0; kt <= qt; ++kt) {
        __syncthreads();   // prior tile's K/V reads done before restage

        // --- stage K tile: Kls[j][d] f16
        {
            const int j  = tid >> 2;
            const int dq = tid & 3;
            const float* src = qkv + (rowbase + kt * 64 + j) * QKVCOLS +
                               CEMB + h * HDIM + dq * 16;
            float4 f0 = *reinterpret_cast<const float4*>(src + 0);
            float4 f1 = *reinterpret_cast<const float4*>(src + 4);
            float4 f2 = *reinterpret_cast<const float4*>(src + 8);
            float4 f3 = *reinterpret_cast<const float4*>(src + 12);
            float fa[8] = {f0.x, f0.y, f0.z, f0.w, f1.x, f1.y, f1.z, f1.w};
            float fb[8] = {f2.x, f2.y, f2.z, f2.w, f3.x, f3.y, f3.z, f3.w};
            half8 h0, h1;
#pragma unroll
            for (int i = 0; i < 8; ++i) { h0[i] = (_Float16)fa[i]; h1[i] = (_Float16)fb[i]; }
            *reinterpret_cast<half8*>(&Kls[j][dq * 16 + 0]) = h0;
            *reinterpret_cast<half8*>(&Kls[j][dq * 16 + 8]) = h1;
        }
        // --- stage V transposed: Vt[d][k], XOR-swizzle on 16B k-blocks
        {
            const int kp = tid >> 3;   // k pair 0..31
            const int dc = tid & 7;    // d chunk of 8
            const float* s0 = qkv + (rowbase + kt * 64 + 2 * kp) * QKVCOLS +
                              2 * CEMB + h * HDIM + dc * 8;
            const float* s1 = s0 + QKVCOLS;
            float4 a0 = *reinterpret_cast<const float4*>(s0);
            float4 a1 = *reinterpret_cast<const float4*>(s0 + 4);
            float4 b0 = *reinterpret_cast<const float4*>(s1);
            float4 b1 = *reinterpret_cast<const float4*>(s1 + 4);
            float va[8] = {a0.x, a0.y, a0.z, a0.w, a1.x, a1.y, a1.z, a1.w};
            float vb[8] = {b0.x, b0.y, b0.z, b0.w, b1.x, b1.y, b1.z, b1.w};
            const int cb = kp >> 2;
#pragma unroll
            for (int i = 0; i < 8; ++i) {
                int d = dc * 8 + i;
                half2v hv;
                hv[0] = (_Float16)va[i];
                hv[1] = (_Float16)vb[i];
                // f16 index: d*64 + swizzled block*8 + (kp&3)*2
                int idx = d * 64 + ((cb ^ (d & 7)) << 3) + (kp & 3) * 2;
                *reinterpret_cast<half2v*>(&Vt[idx]) = hv;
            }
        }
        __syncthreads();

        // --- S = (Q/8) K^T : 8 MFMA
        f32x4 S[4];
#pragma unroll
        for (int c = 0; c < 4; ++c) {
            f32x4 acc = (f32x4){0.f, 0.f, 0.f, 0.f};
#pragma unroll
            for (int kc = 0; kc < 2; ++kc) {
                half8 kb = *reinterpret_cast<const half8*>(
                    &Kls[c * 16 + lj][kc * 32 + lg * 8]);
                acc = __builtin_amdgcn_mfma_f32_16x16x32_f16(qf[kc], kb, acc, 0, 0, 0);
            }
            S[c] = acc;
        }

        // --- causal mask (diagonal tile only)
        if (kt == qt) {
#pragma unroll
            for (int c = 0; c < 4; ++c) {
                int kk = c * 16 + lj;
#pragma unroll
                for (int r = 0; r < 4; ++r)
                    if (kk > w * 16 + lg * 4 + r) S[c][r] = -INFINITY;
            }
        }

        // --- online softmax (rows live across the 16 lanes of group lg)
        float pm[4];
#pragma unroll
        for (int r = 0; r < 4; ++r)
            pm[r] = fmaxf(fmaxf(S[0][r], S[1][r]), fmaxf(S[2][r], S[3][r]));
#pragma unroll
        for (int r = 0; r < 4; ++r) {
            pm[r] = fmaxf(pm[r], __shfl_xor(pm[r], 1));
            pm[r] = fmaxf(pm[r], __shfl_xor(pm[r], 2));
            pm[r] = fmaxf(pm[r], __shfl_xor(pm[r], 4));
            pm[r] = fmaxf(pm[r], __shfl_xor(pm[r], 8));
        }
        float sc[4];
#pragma unroll
        for (int r = 0; r < 4; ++r) {
            float mnew = fmaxf(mrow[r], pm[r]);
            sc[r]   = __expf(mrow[r] - mnew);   // exp(-inf)=0 first tile
            mrow[r] = mnew;
        }
        float ps[4] = {0.f, 0.f, 0.f, 0.f};
#pragma unroll
        for (int c = 0; c < 4; ++c)
#pragma unroll
            for (int r = 0; r < 4; ++r) {
                float pv = __expf(S[c][r] - mrow[r]);
                S[c][r] = pv;
                ps[r] += pv;
            }
#pragma unroll
        for (int r = 0; r < 4; ++r) {
            ps[r] += __shfl_xor(ps[r], 1);
            ps[r] += __shfl_xor(ps[r], 2);
            ps[r] += __shfl_xor(ps[r], 4);
            ps[r] += __shfl_xor(ps[r], 8);
            lrow[r] = lrow[r] * sc[r] + ps[r];
        }
#pragma unroll
        for (int dt = 0; dt < 4; ++dt)
#pragma unroll
            for (int r = 0; r < 4; ++r) O[dt][r] *= sc[r];

        // --- P -> f16 -> per-wave LDS (A-layout transpose), same-wave RAW
#pragma unroll
        for (int c = 0; c < 4; ++c)
#pragma unroll
            for (int r = 0; r < 4; ++r)
                Pls[w][lg * 4 + r][c * 16 + lj] = (_Float16)S[c][r];

        half8 pa0 = *reinterpret_cast<const half8*>(&Pls[w][lj][lg * 8]);
        half8 pa1 = *reinterpret_cast<const half8*>(&Pls[w][lj][32 + lg * 8]);

        // --- O += P V : 8 MFMA, B-frag from swizzled Vt
#pragma unroll
        for (int dt = 0; dt < 4; ++dt) {
            const int row = dt * 16 + lj;
#pragma unroll
            for (int kc = 0; kc < 2; ++kc) {
                const int cb = kc * 4 + lg;
                half8 vbf = *reinterpret_cast<const half8*>(
                    &Vt[row * 64 + ((cb ^ (row & 7)) << 3)]);
                O[dt] = __builtin_amdgcn_mfma_f32_16x16x32_f16(
                    kc ? pa1 : pa0, vbf, O[dt], 0, 0, 0);
            }
        }
    }

    // --- epilogue: normalize and store
    float inv[4];
#pragma unroll
    for (int r = 0; r < 4; ++r) inv[r] = 1.0f / lrow[r];
#pragma unroll
    for (int dt = 0; dt < 4; ++dt)
#pragma unroll
        for (int r = 0; r < 4; ++r)
            y[(rowbase + q0 + w * 16 + lg * 4 + r) * CEMB + h * HDIM +
              dt * 16 + lj] = O[dt][r] * inv[r];
}

// ---------------------------------------------------------------------------
extern "C" void kernel_launch(void* const* d_in, const int* in_sizes, int n_in,
                              void* d_out, int out_size, void* d_ws, size_t ws_size,
                              hipStream_t stream) {
    const float* x     = (const float*)d_in[0];
    const float* Wqkv  = (const float*)d_in[1];
    const float* bqkv  = (const float*)d_in[2];
    const float* Wproj = (const float*)d_in[3];
    const float* bproj = (const float*)d_in[4];
    float* out = (float*)d_out;

    float* qkv = (float*)d_ws;
    float* yb  = (float*)((char*)d_ws + (size_t)BTROWS * QKVCOLS * sizeof(float));

    {
        dim3 grid((BTROWS / 128) * (QKVCOLS / 128));
        gemm_bias_kernel<128, 128, 16><<<grid, 256, 0, stream>>>(
            x, Wqkv, bqkv, qkv, BTROWS, QKVCOLS, CEMB);
    }
    {
        dim3 grid(BATCH * NHEAD * (TSEQ / 64));   // 1536
        attn_kernel<<<grid, 256, 0, stream>>>(qkv, yb);
    }
    {
        dim3 grid((BTROWS / 128) * (CEMB / 128));
        gemm_bias_kernel<128, 128, 16><<<grid, 256, 0, stream>>>(
            yb, Wproj, bproj, out, BTROWS, CEMB, CEMB);
    }
}

// Round 3
// 348.652 us; speedup vs baseline: 6.0096x; 2.2680x over previous
//
#include <hip/hip_runtime.h>
#include <math.h>

// Problem constants: B=4, T=2048, C=768, H=12, D=64
#define BATCH   4
#define TSEQ    2048
#define CEMB    768
#define NHEAD   12
#define HDIM    64
#define BTROWS  (BATCH * TSEQ)      // 8192
#define QKVCOLS (3 * CEMB)          // 2304

typedef _Float16 half8  __attribute__((ext_vector_type(8)));
typedef _Float16 half2v __attribute__((ext_vector_type(2)));
typedef float    f32x4  __attribute__((ext_vector_type(4)));

// async global->LDS, 16B per lane. LDS dest = base (wave-uniform) + lane*16.
__device__ inline void gload16(const void* g, void* l) {
    __builtin_amdgcn_global_load_lds(
        (const __attribute__((address_space(1))) void*)g,
        (__attribute__((address_space(3))) void*)l, 16, 0, 0);
}

// ---------------------------------------------------------------------------
// fp32 -> f16 elementwise convert (8 elems/thread, exact grid)
// ---------------------------------------------------------------------------
__global__ __launch_bounds__(256)
void convert_f16_kernel(const float* __restrict__ in, _Float16* __restrict__ out) {
    const int i = blockIdx.x * 256 + threadIdx.x;
    const float4* p = reinterpret_cast<const float4*>(in) + (size_t)i * 2;
    float4 a = p[0], b = p[1];
    half8 h;
    h[0] = (_Float16)a.x; h[1] = (_Float16)a.y; h[2] = (_Float16)a.z; h[3] = (_Float16)a.w;
    h[4] = (_Float16)b.x; h[5] = (_Float16)b.y; h[6] = (_Float16)b.z; h[7] = (_Float16)b.w;
    *reinterpret_cast<half8*>(out + (size_t)i * 8) = h;
}

// ---------------------------------------------------------------------------
// fp32 [K][N] -> f16 [N][K] transpose-convert, 32x32 tiles via LDS
// ---------------------------------------------------------------------------
__global__ __launch_bounds__(256)
void transpose_f16_kernel(const float* __restrict__ in, _Float16* __restrict__ out,
                          int K, int N) {
    __shared__ float t[32][33];
    const int ntx = N >> 5;
    const int bx = blockIdx.x % ntx, by = blockIdx.x / ntx;
    const int c0 = bx << 5, r0 = by << 5;
    const int tx = threadIdx.x & 31, ty = threadIdx.x >> 5;   // ty 0..7
#pragma unroll
    for (int j = 0; j < 4; ++j)
        t[ty + j * 8][tx] = in[(size_t)(r0 + ty + j * 8) * N + c0 + tx];
    __syncthreads();
#pragma unroll
    for (int j = 0; j < 4; ++j)
        out[(size_t)(c0 + ty + j * 8) * K + r0 + tx] = (_Float16)t[tx][ty + j * 8];
}

// ---------------------------------------------------------------------------
// f16 MFMA GEMM: C[M][N] = A[M][K] @ Bt[N][K]^T + bias[N]
// A, Bt f16 row-major; fp32 accumulate; OutT in {float, _Float16}.
// 128x128 tile, BK=32, 256 thr = 4 waves (2x2), each wave 64x64 = 4x4 frags
// of mfma_f32_16x16x32_f16. Staging via global_load_lds width-16 into LINEAR
// LDS; bank-spread achieved by pre-swizzling the GLOBAL source address
// (slot kgp = kg ^ ((row>>1)&3)) and applying the same XOR on ds_read.
// Frag reads then hit 8 distinct 16B slots per 128B window -> 2-way (free).
// ---------------------------------------------------------------------------
template <typename OutT>
__global__ __launch_bounds__(256)
void gemm_f16_kernel(const _Float16* __restrict__ A, const _Float16* __restrict__ Bt,
                     const float* __restrict__ bias, OutT* __restrict__ C,
                     int M, int N, int K) {
    __shared__ _Float16 As[128 * 32];   // 8 KB, linear slots of 8 f16
    __shared__ _Float16 Bs[128 * 32];   // 8 KB

    const int tid = threadIdx.x;
    const int w  = tid >> 6, l = tid & 63;
    const int ntx = N >> 7;
    const int bx = blockIdx.x % ntx, by = blockIdx.x / ntx;
    const int m0 = by << 7, n0 = bx << 7;
    const int wr = w >> 1, wc = w & 1;        // wave -> 64x64 quadrant
    const int lj = l & 15, lg = l >> 4;

    f32x4 acc[4][4];
#pragma unroll
    for (int i = 0; i < 4; ++i)
#pragma unroll
        for (int j = 0; j < 4; ++j) acc[i][j] = (f32x4){0.f, 0.f, 0.f, 0.f};

    // per-lane staging geometry (constant across K-steps except k0)
    int srow[2], skg[2];
#pragma unroll
    for (int i = 0; i < 2; ++i) {
        int s   = w * 128 + i * 64 + l;       // linear 16B slot 0..511
        srow[i] = s >> 2;                     // tile row 0..127
        skg[i]  = (s & 3) ^ ((srow[i] >> 1) & 3);   // source k-chunk
    }

    for (int k0 = 0; k0 < K; k0 += 32) {
        __syncthreads();   // previous iteration's frag reads complete
#pragma unroll
        for (int i = 0; i < 2; ++i) {
            gload16(A + (size_t)(m0 + srow[i]) * K + k0 + skg[i] * 8,
                    As + ((size_t)w * 128 + i * 64) * 8);
            gload16(Bt + (size_t)(n0 + srow[i]) * K + k0 + skg[i] * 8,
                    Bs + ((size_t)w * 128 + i * 64) * 8);
        }
        __syncthreads();   // compiler drains vmcnt(0) before barrier

        half8 af[4], bf[4];
#pragma unroll
        for (int mi = 0; mi < 4; ++mi) {
            int r = wr * 64 + mi * 16 + lj;
            af[mi] = *reinterpret_cast<const half8*>(
                &As[(r * 4 + (lg ^ ((r >> 1) & 3))) * 8]);
        }
#pragma unroll
        for (int ni = 0; ni < 4; ++ni) {
            int r = wc * 64 + ni * 16 + lj;
            bf[ni] = *reinterpret_cast<const half8*>(
                &Bs[(r * 4 + (lg ^ ((r >> 1) & 3))) * 8]);
        }
#pragma unroll
        for (int mi = 0; mi < 4; ++mi)
#pragma unroll
            for (int ni = 0; ni < 4; ++ni)
                acc[mi][ni] = __builtin_amdgcn_mfma_f32_16x16x32_f16(
                    af[mi], bf[ni], acc[mi][ni], 0, 0, 0);
    }

    // epilogue: bias add (fp32), store OutT
#pragma unroll
    for (int mi = 0; mi < 4; ++mi) {
        int row = m0 + wr * 64 + mi * 16 + lg * 4;
#pragma unroll
        for (int ni = 0; ni < 4; ++ni) {
            int col = n0 + wc * 64 + ni * 16 + lj;
            float bv = bias[col];
#pragma unroll
            for (int r = 0; r < 4; ++r)
                C[(size_t)(row + r) * N + col] = (OutT)(acc[mi][ni][r] + bv);
        }
    }
}

// ---------------------------------------------------------------------------
// Flash attention, f16 MFMA, f16 qkv input, f16 y output.
// Structure identical to round-2 (verified); staging now loads f16 directly.
// ---------------------------------------------------------------------------
__global__ __launch_bounds__(256)
void attn_kernel(const _Float16* __restrict__ qkv, _Float16* __restrict__ y) {
    __shared__ _Float16 Kls[64][72];        // 9216 B
    __shared__ _Float16 Vt[64 * 64];        // 8192 B, swizzled Vt[d][k]
    __shared__ _Float16 Pls[4][16][72];     // 9216 B, per-wave private

    const int tid = threadIdx.x;
    const int w   = tid >> 6;
    const int l   = tid & 63;
    const int lj  = l & 15;
    const int lg  = l >> 4;

    const int qt = blockIdx.x & 31;
    const int bh = blockIdx.x >> 5;
    const int h  = bh % NHEAD;
    const int b  = bh / NHEAD;
    const int q0 = qt * 64;
    const size_t rowbase = (size_t)b * TSEQ;

    // Q fragments (scaled by 1/8 -- exact in f16)
    half8 qf[2];
    {
        const _Float16* qrow =
            qkv + (rowbase + q0 + w * 16 + lj) * QKVCOLS + h * HDIM;
#pragma unroll
        for (int kc = 0; kc < 2; ++kc) {
            half8 hv = *reinterpret_cast<const half8*>(qrow + kc * 32 + lg * 8);
#pragma unroll
            for (int i = 0; i < 8; ++i) hv[i] = hv[i] * (_Float16)0.125f;
            qf[kc] = hv;
        }
    }

    f32x4 O[4];
#pragma unroll
    for (int dt = 0; dt < 4; ++dt) O[dt] = (f32x4){0.f, 0.f, 0.f, 0.f};
    float mrow[4] = {-INFINITY, -INFINITY, -INFINITY, -INFINITY};
    float lrow[4] = {0.f, 0.f, 0.f, 0.f};

    for (int kt = 0; kt <= qt; ++kt) {
        __syncthreads();

        // stage K: Kls[j][d], 512 chunks of 8 f16
#pragma unroll
        for (int i = 0; i < 2; ++i) {
            int li  = tid + i * 256;
            int row = li >> 3;
            int dq  = li & 7;
            *reinterpret_cast<half8*>(&Kls[row][dq * 8]) =
                *reinterpret_cast<const half8*>(
                    &qkv[(rowbase + kt * 64 + row) * QKVCOLS + CEMB + h * HDIM + dq * 8]);
        }
        // stage V transposed + swizzled
        {
            const int kp = tid >> 3;   // 0..31
            const int dc = tid & 7;    // 0..7
            const _Float16* s0 = qkv + (rowbase + kt * 64 + 2 * kp) * QKVCOLS +
                                 2 * CEMB + h * HDIM + dc * 8;
            half8 v0 = *reinterpret_cast<const half8*>(s0);
            half8 v1 = *reinterpret_cast<const half8*>(s0 + QKVCOLS);
            const int cb = kp >> 2;
#pragma unroll
            for (int i = 0; i < 8; ++i) {
                int d = dc * 8 + i;
                half2v hv; hv[0] = v0[i]; hv[1] = v1[i];
                int idx = d * 64 + ((cb ^ (d & 7)) << 3) + (kp & 3) * 2;
                *reinterpret_cast<half2v*>(&Vt[idx]) = hv;
            }
        }
        __syncthreads();

        // S = (Q/8) K^T
        f32x4 S[4];
#pragma unroll
        for (int c = 0; c < 4; ++c) {
            f32x4 acc = (f32x4){0.f, 0.f, 0.f, 0.f};
#pragma unroll
            for (int kc = 0; kc < 2; ++kc) {
                half8 kb = *reinterpret_cast<const half8*>(
                    &Kls[c * 16 + lj][kc * 32 + lg * 8]);
                acc = __builtin_amdgcn_mfma_f32_16x16x32_f16(qf[kc], kb, acc, 0, 0, 0);
            }
            S[c] = acc;
        }

        if (kt == qt) {
#pragma unroll
            for (int c = 0; c < 4; ++c) {
                int kk = c * 16 + lj;
#pragma unroll
                for (int r = 0; r < 4; ++r)
                    if (kk > w * 16 + lg * 4 + r) S[c][r] = -INFINITY;
            }
        }

        float pm[4];
#pragma unroll
        for (int r = 0; r < 4; ++r)
            pm[r] = fmaxf(fmaxf(S[0][r], S[1][r]), fmaxf(S[2][r], S[3][r]));
#pragma unroll
        for (int r = 0; r < 4; ++r) {
            pm[r] = fmaxf(pm[r], __shfl_xor(pm[r], 1));
            pm[r] = fmaxf(pm[r], __shfl_xor(pm[r], 2));
            pm[r] = fmaxf(pm[r], __shfl_xor(pm[r], 4));
            pm[r] = fmaxf(pm[r], __shfl_xor(pm[r], 8));
        }
        float sc[4];
#pragma unroll
        for (int r = 0; r < 4; ++r) {
            float mnew = fmaxf(mrow[r], pm[r]);
            sc[r]   = __expf(mrow[r] - mnew);
            mrow[r] = mnew;
        }
        float ps[4] = {0.f, 0.f, 0.f, 0.f};
#pragma unroll
        for (int c = 0; c < 4; ++c)
#pragma unroll
            for (int r = 0; r < 4; ++r) {
                float pv = __expf(S[c][r] - mrow[r]);
                S[c][r] = pv;
                ps[r] += pv;
            }
#pragma unroll
        for (int r = 0; r < 4; ++r) {
            ps[r] += __shfl_xor(ps[r], 1);
            ps[r] += __shfl_xor(ps[r], 2);
            ps[r] += __shfl_xor(ps[r], 4);
            ps[r] += __shfl_xor(ps[r], 8);
            lrow[r] = lrow[r] * sc[r] + ps[r];
        }
#pragma unroll
        for (int dt = 0; dt < 4; ++dt)
#pragma unroll
            for (int r = 0; r < 4; ++r) O[dt][r] *= sc[r];

        // P -> f16 -> per-wave LDS transpose (same-wave RAW)
#pragma unroll
        for (int c = 0; c < 4; ++c)
#pragma unroll
            for (int r = 0; r < 4; ++r)
                Pls[w][lg * 4 + r][c * 16 + lj] = (_Float16)S[c][r];

        half8 pa0 = *reinterpret_cast<const half8*>(&Pls[w][lj][lg * 8]);
        half8 pa1 = *reinterpret_cast<const half8*>(&Pls[w][lj][32 + lg * 8]);

        // O += P V
#pragma unroll
        for (int dt = 0; dt < 4; ++dt) {
            const int row = dt * 16 + lj;
#pragma unroll
            for (int kc = 0; kc < 2; ++kc) {
                const int cb = kc * 4 + lg;
                half8 vbf = *reinterpret_cast<const half8*>(
                    &Vt[row * 64 + ((cb ^ (row & 7)) << 3)]);
                O[dt] = __builtin_amdgcn_mfma_f32_16x16x32_f16(
                    kc ? pa1 : pa0, vbf, O[dt], 0, 0, 0);
            }
        }
    }

    float inv[4];
#pragma unroll
    for (int r = 0; r < 4; ++r) inv[r] = 1.0f / lrow[r];
#pragma unroll
    for (int dt = 0; dt < 4; ++dt)
#pragma unroll
        for (int r = 0; r < 4; ++r)
            y[(rowbase + q0 + w * 16 + lg * 4 + r) * CEMB + h * HDIM +
              dt * 16 + lj] = (_Float16)(O[dt][r] * inv[r]);
}

// ---------------------------------------------------------------------------
extern "C" void kernel_launch(void* const* d_in, const int* in_sizes, int n_in,
                              void* d_out, int out_size, void* d_ws, size_t ws_size,
                              hipStream_t stream) {
    const float* x     = (const float*)d_in[0];
    const float* Wqkv  = (const float*)d_in[1];
    const float* bqkv  = (const float*)d_in[2];
    const float* Wproj = (const float*)d_in[3];
    const float* bproj = (const float*)d_in[4];
    float* out = (float*)d_out;

    // workspace layout (f16):
    char* ws = (char*)d_ws;
    _Float16* qkvh   = (_Float16*)ws;                                   ws += (size_t)BTROWS * QKVCOLS * 2;  // 37.7 MB
    _Float16* yh     = (_Float16*)ws;                                   ws += (size_t)BTROWS * CEMB * 2;     // 12.6 MB
    _Float16* xh     = (_Float16*)ws;                                   ws += (size_t)BTROWS * CEMB * 2;     // 12.6 MB
    _Float16* Wqkvt  = (_Float16*)ws;                                   ws += (size_t)QKVCOLS * CEMB * 2;    // 3.5 MB
    _Float16* Wprojt = (_Float16*)ws;

    // prep: convert + transpose to f16
    convert_f16_kernel<<<(BTROWS * CEMB) / (256 * 8), 256, 0, stream>>>(x, xh);
    transpose_f16_kernel<<<(CEMB / 32) * (QKVCOLS / 32), 256, 0, stream>>>(
        Wqkv, Wqkvt, CEMB, QKVCOLS);
    transpose_f16_kernel<<<(CEMB / 32) * (CEMB / 32), 256, 0, stream>>>(
        Wproj, Wprojt, CEMB, CEMB);

    // 1) qkv = x @ Wqkv + bqkv   (f16 out)
    gemm_f16_kernel<_Float16><<<(BTROWS / 128) * (QKVCOLS / 128), 256, 0, stream>>>(
        xh, Wqkvt, bqkv, qkvh, BTROWS, QKVCOLS, CEMB);

    // 2) causal attention -> yh f16
    attn_kernel<<<BATCH * NHEAD * (TSEQ / 64), 256, 0, stream>>>(qkvh, yh);

    // 3) out = y @ Wproj + bproj  (fp32 out)
    gemm_f16_kernel<float><<<(BTROWS / 128) * (CEMB / 128), 256, 0, stream>>>(
        yh, Wprojt, bproj, out, BTROWS, CEMB, CEMB);
}

// Round 5
// 290.215 us; speedup vs baseline: 7.2197x; 1.2014x over previous
//
#include <hip/hip_runtime.h>
#include <math.h>

// Problem constants: B=4, T=2048, C=768, H=12, D=64
#define BATCH   4
#define TSEQ    2048
#define CEMB    768
#define NHEAD   12
#define HDIM    64
#define BTROWS  (BATCH * TSEQ)      // 8192
#define QKVCOLS (3 * CEMB)          // 2304
#define NQT     (TSEQ / 64)         // 32 q-tiles per (b,h)

typedef _Float16 half8  __attribute__((ext_vector_type(8)));
typedef _Float16 half2v __attribute__((ext_vector_type(2)));
typedef float    f32x4  __attribute__((ext_vector_type(4)));

// async global->LDS, 16B/lane. LDS dest = wave-uniform base + lane*16.
__device__ inline void gload16(const void* g, void* l) {
    __builtin_amdgcn_global_load_lds(
        (const __attribute__((address_space(1))) void*)g,
        (__attribute__((address_space(3))) void*)l, 16, 0, 0);
}

// ---------------------------------------------------------------------------
// fp32 -> f16 elementwise convert (8 elems/thread)
// ---------------------------------------------------------------------------
__global__ __launch_bounds__(256)
void convert_f16_kernel(const float* __restrict__ in, _Float16* __restrict__ out) {
    const int i = blockIdx.x * 256 + threadIdx.x;
    const float4* p = reinterpret_cast<const float4*>(in) + (size_t)i * 2;
    float4 a = p[0], b = p[1];
    half8 h;
    h[0] = (_Float16)a.x; h[1] = (_Float16)a.y; h[2] = (_Float16)a.z; h[3] = (_Float16)a.w;
    h[4] = (_Float16)b.x; h[5] = (_Float16)b.y; h[6] = (_Float16)b.z; h[7] = (_Float16)b.w;
    *reinterpret_cast<half8*>(out + (size_t)i * 8) = h;
}

// ---------------------------------------------------------------------------
// fp32 [K][N] -> f16 [N][K] transpose-convert, 32x32 tiles via LDS
// ---------------------------------------------------------------------------
__global__ __launch_bounds__(256)
void transpose_f16_kernel(const float* __restrict__ in, _Float16* __restrict__ out,
                          int K, int N) {
    __shared__ float t[32][33];
    const int ntx = N >> 5;
    const int bx = blockIdx.x % ntx, by = blockIdx.x / ntx;
    const int c0 = bx << 5, r0 = by << 5;
    const int tx = threadIdx.x & 31, ty = threadIdx.x >> 5;
#pragma unroll
    for (int j = 0; j < 4; ++j)
        t[ty + j * 8][tx] = in[(size_t)(r0 + ty + j * 8) * N + c0 + tx];
    __syncthreads();
#pragma unroll
    for (int j = 0; j < 4; ++j)
        out[(size_t)(c0 + ty + j * 8) * K + r0 + tx] = (_Float16)t[tx][ty + j * 8];
}

// ---------------------------------------------------------------------------
// f16 MFMA GEMM: C[M][N] = A[M][K] @ Bt[N][K]^T + bias[N]
// 128x128 tile, BK=64, 4 waves (2x2), 4x4 frags of mfma_f32_16x16x32_f16.
// Staging: global_load_lds w=16 into LINEAR LDS; source chunk pre-XORed by
// (row&7), reads apply the same XOR -> 2-way banks (free), 32 MFMA/barrier.
// ---------------------------------------------------------------------------
template <typename OutT>
__global__ __launch_bounds__(256)
void gemm_f16_kernel(const _Float16* __restrict__ A, const _Float16* __restrict__ Bt,
                     const float* __restrict__ bias, OutT* __restrict__ C,
                     int M, int N, int K) {
    __shared__ _Float16 As[128 * 64];   // 16 KB
    __shared__ _Float16 Bs[128 * 64];   // 16 KB

    const int tid = threadIdx.x;
    const int w  = tid >> 6, l = tid & 63;
    const int ntx = N >> 7;
    const int bx = blockIdx.x % ntx, by = blockIdx.x / ntx;
    const int m0 = by << 7, n0 = bx << 7;
    const int wr = w >> 1, wc = w & 1;
    const int lj = l & 15, lg = l >> 4;

    f32x4 acc[4][4];
#pragma unroll
    for (int i = 0; i < 4; ++i)
#pragma unroll
        for (int j = 0; j < 4; ++j) acc[i][j] = (f32x4){0.f, 0.f, 0.f, 0.f};

    // staging geometry: 4 slots/lane/matrix; slot s=(row,ch), src chunk ch^(row&7)
    int srow[4], sch[4];
#pragma unroll
    for (int i = 0; i < 4; ++i) {
        int s   = w * 256 + i * 64 + l;
        srow[i] = s >> 3;
        sch[i]  = (s & 7) ^ (srow[i] & 7);
    }

    for (int k0 = 0; k0 < K; k0 += 64) {
        __syncthreads();
#pragma unroll
        for (int i = 0; i < 4; ++i) {
            gload16(A + (size_t)(m0 + srow[i]) * K + k0 + sch[i] * 8,
                    As + ((size_t)w * 256 + i * 64) * 8);
            gload16(Bt + (size_t)(n0 + srow[i]) * K + k0 + sch[i] * 8,
                    Bs + ((size_t)w * 256 + i * 64) * 8);
        }
        __syncthreads();

#pragma unroll
        for (int kc = 0; kc < 2; ++kc) {
            half8 af[4], bf[4];
#pragma unroll
            for (int mi = 0; mi < 4; ++mi) {
                int r = wr * 64 + mi * 16 + lj;
                af[mi] = *reinterpret_cast<const half8*>(
                    &As[r * 64 + (((kc * 4 + lg) ^ (r & 7)) << 3)]);
            }
#pragma unroll
            for (int ni = 0; ni < 4; ++ni) {
                int r = wc * 64 + ni * 16 + lj;
                bf[ni] = *reinterpret_cast<const half8*>(
                    &Bs[r * 64 + (((kc * 4 + lg) ^ (r & 7)) << 3)]);
            }
#pragma unroll
            for (int mi = 0; mi < 4; ++mi)
#pragma unroll
                for (int ni = 0; ni < 4; ++ni)
                    acc[mi][ni] = __builtin_amdgcn_mfma_f32_16x16x32_f16(
                        af[mi], bf[ni], acc[mi][ni], 0, 0, 0);
        }
    }

#pragma unroll
    for (int mi = 0; mi < 4; ++mi) {
        int row = m0 + wr * 64 + mi * 16 + lg * 4;
#pragma unroll
        for (int ni = 0; ni < 4; ++ni) {
            int col = n0 + wc * 64 + ni * 16 + lj;
            float bv = bias[col];
#pragma unroll
            for (int r = 0; r < 4; ++r)
                C[(size_t)(row + r) * N + col] = (OutT)(acc[mi][ni][r] + bv);
        }
    }
}

// ---------------------------------------------------------------------------
// Flash attention, f16 MFMA. PAIRED q-tiles for balance: block p handles
// q-tiles {p, 31-p} -> every block does exactly 33 tile-computes; K/V staged
// once per kt and shared. Grid 48*16=768 = exactly 3 blocks/CU, all resident.
// K: linear LDS via global_load_lds, source chunk ^= (row&7)  (conflict-free).
// Vt/Pls: rows padded to 68 f16 (stride=34 words) -> ~2-way banks (free).
// ---------------------------------------------------------------------------
__global__ __launch_bounds__(256)
void attn_kernel(const _Float16* __restrict__ qkv, _Float16* __restrict__ y) {
    __shared__ _Float16 Kls[64 * 64];       // 8 KB, linear XOR-chunk layout
    __shared__ _Float16 Vt[64 * 68];        // 8.5 KB  Vt[d][k-slots]
    __shared__ _Float16 Pls[4][16][68];     // 8.5 KB per-wave private

    const int tid = threadIdx.x;
    const int w   = tid >> 6;
    const int l   = tid & 63;
    const int lj  = l & 15;
    const int lg  = l >> 4;

    const int pi = blockIdx.x & 15;          // pair index 0..15
    const int bh = blockIdx.x >> 4;
    const int h  = bh % NHEAD;
    const int b  = bh / NHEAD;
    const int qt0 = pi;                      // tile A
    const int qt1 = NQT - 1 - pi;            // tile B (>= 16)
    const size_t rowbase = (size_t)b * TSEQ;

    // --- Q fragments for both tiles (scaled by 1/8)
    half8 qf[2][2];
#pragma unroll
    for (int t = 0; t < 2; ++t) {
        const int q0 = (t ? qt1 : qt0) * 64;
        const _Float16* qrow =
            qkv + (rowbase + q0 + w * 16 + lj) * QKVCOLS + h * HDIM;
#pragma unroll
        for (int kc = 0; kc < 2; ++kc) {
            half8 hv = *reinterpret_cast<const half8*>(qrow + kc * 32 + lg * 8);
#pragma unroll
            for (int i = 0; i < 8; ++i) hv[i] = hv[i] * (_Float16)0.125f;
            qf[t][kc] = hv;
        }
    }

    f32x4 O[2][4];
    float mrow[2][4], lrow[2][4];
#pragma unroll
    for (int t = 0; t < 2; ++t)
#pragma unroll
        for (int dt = 0; dt < 4; ++dt) {
            O[t][dt] = (f32x4){0.f, 0.f, 0.f, 0.f};
            mrow[t][dt] = -INFINITY;
            lrow[t][dt] = 0.f;
        }

    // K staging geometry: 512 slots of 16B; wave w covers slots w*128..+127
    int ksrow[2], ksch[2];
#pragma unroll
    for (int i = 0; i < 2; ++i) {
        int s    = w * 128 + i * 64 + l;
        ksrow[i] = s >> 3;
        ksch[i]  = (s & 7) ^ (ksrow[i] & 7);
    }

    for (int kt = 0; kt <= qt1; ++kt) {
        __syncthreads();   // prior tile's LDS reads complete

        // --- stage K: async DMA, linear dest, pre-swizzled source
#pragma unroll
        for (int i = 0; i < 2; ++i)
            gload16(qkv + (rowbase + kt * 64 + ksrow[i]) * QKVCOLS +
                        CEMB + h * HDIM + ksch[i] * 8,
                    Kls + ((size_t)w * 128 + i * 64) * 8);

        // --- stage V transposed, rows padded to 68
        {
            const int kp = tid >> 3;   // 0..31 (k pairs)
            const int dc = tid & 7;    // 0..7  (d chunks of 8)
            const _Float16* s0 = qkv + (rowbase + kt * 64 + 2 * kp) * QKVCOLS +
                                 2 * CEMB + h * HDIM + dc * 8;
            half8 v0 = *reinterpret_cast<const half8*>(s0);
            half8 v1 = *reinterpret_cast<const half8*>(s0 + QKVCOLS);
            const int cb = kp >> 2;
#pragma unroll
            for (int i = 0; i < 8; ++i) {
                int d = dc * 8 + i;
                half2v hv; hv[0] = v0[i]; hv[1] = v1[i];
                int idx = d * 68 + ((cb ^ (d & 7)) << 3) + (kp & 3) * 2;
                *reinterpret_cast<half2v*>(&Vt[idx]) = hv;
            }
        }
        __syncthreads();

        // --- compute for each active q-tile (uniform branches)
#pragma unroll
        for (int t = 0; t < 2; ++t) {
            const int qt = t ? qt1 : qt0;
            if (kt > qt) continue;     // only tile A goes inactive (kt>qt0)

            // S = (Q/8) K^T   (K frags from XOR-chunk linear LDS)
            f32x4 S[4];
#pragma unroll
            for (int c = 0; c < 4; ++c) {
                f32x4 acc = (f32x4){0.f, 0.f, 0.f, 0.f};
#pragma unroll
                for (int kc = 0; kc < 2; ++kc) {
                    int r = c * 16 + lj;
                    half8 kb = *reinterpret_cast<const half8*>(
                        &Kls[r * 64 + (((kc * 4 + lg) ^ (r & 7)) << 3)]);
                    acc = __builtin_amdgcn_mfma_f32_16x16x32_f16(
                        qf[t][kc], kb, acc, 0, 0, 0);
                }
                S[c] = acc;
            }

            if (kt == qt) {            // causal mask on diagonal tile
#pragma unroll
                for (int c = 0; c < 4; ++c) {
                    int kk = c * 16 + lj;
#pragma unroll
                    for (int r = 0; r < 4; ++r)
                        if (kk > w * 16 + lg * 4 + r) S[c][r] = -INFINITY;
                }
            }

            // online softmax
            float pm[4];
#pragma unroll
            for (int r = 0; r < 4; ++r)
                pm[r] = fmaxf(fmaxf(S[0][r], S[1][r]), fmaxf(S[2][r], S[3][r]));
#pragma unroll
            for (int r = 0; r < 4; ++r) {
                pm[r] = fmaxf(pm[r], __shfl_xor(pm[r], 1));
                pm[r] = fmaxf(pm[r], __shfl_xor(pm[r], 2));
                pm[r] = fmaxf(pm[r], __shfl_xor(pm[r], 4));
                pm[r] = fmaxf(pm[r], __shfl_xor(pm[r], 8));
            }
            float sc[4];
#pragma unroll
            for (int r = 0; r < 4; ++r) {
                float mnew = fmaxf(mrow[t][r], pm[r]);
                sc[r] = __expf(mrow[t][r] - mnew);
                mrow[t][r] = mnew;
            }
            float ps[4] = {0.f, 0.f, 0.f, 0.f};
#pragma unroll
            for (int c = 0; c < 4; ++c)
#pragma unroll
                for (int r = 0; r < 4; ++r) {
                    float pv = __expf(S[c][r] - mrow[t][r]);
                    S[c][r] = pv;
                    ps[r] += pv;
                }
#pragma unroll
            for (int r = 0; r < 4; ++r) {
                ps[r] += __shfl_xor(ps[r], 1);
                ps[r] += __shfl_xor(ps[r], 2);
                ps[r] += __shfl_xor(ps[r], 4);
                ps[r] += __shfl_xor(ps[r], 8);
                lrow[t][r] = lrow[t][r] * sc[r] + ps[r];
            }
#pragma unroll
            for (int dt = 0; dt < 4; ++dt)
#pragma unroll
                for (int r = 0; r < 4; ++r) O[t][dt][r] *= sc[r];

            // P -> f16 -> per-wave LDS transpose (same-wave RAW)
#pragma unroll
            for (int c = 0; c < 4; ++c)
#pragma unroll
                for (int r = 0; r < 4; ++r)
                    Pls[w][lg * 4 + r][c * 16 + lj] = (_Float16)S[c][r];

            half8 pa0 = *reinterpret_cast<const half8*>(&Pls[w][lj][lg * 8]);
            half8 pa1 = *reinterpret_cast<const half8*>(&Pls[w][lj][32 + lg * 8]);

            // O += P V  (B frags from padded swizzled Vt)
#pragma unroll
            for (int dt = 0; dt < 4; ++dt) {
                const int row = dt * 16 + lj;
#pragma unroll
                for (int kc = 0; kc < 2; ++kc) {
                    const int cb = kc * 4 + lg;
                    half8 vbf = *reinterpret_cast<const half8*>(
                        &Vt[row * 68 + ((cb ^ (row & 7)) << 3)]);
                    O[t][dt] = __builtin_amdgcn_mfma_f32_16x16x32_f16(
                        kc ? pa1 : pa0, vbf, O[t][dt], 0, 0, 0);
                }
            }
        }
    }

    // --- epilogue: normalize and store both tiles
#pragma unroll
    for (int t = 0; t < 2; ++t) {
        const int q0 = (t ? qt1 : qt0) * 64;
        float inv[4];
#pragma unroll
        for (int r = 0; r < 4; ++r) inv[r] = 1.0f / lrow[t][r];
#pragma unroll
        for (int dt = 0; dt < 4; ++dt)
#pragma unroll
            for (int r = 0; r < 4; ++r)
                y[(rowbase + q0 + w * 16 + lg * 4 + r) * CEMB + h * HDIM +
                  dt * 16 + lj] = (_Float16)(O[t][dt][r] * inv[r]);
    }
}

// ---------------------------------------------------------------------------
extern "C" void kernel_launch(void* const* d_in, const int* in_sizes, int n_in,
                              void* d_out, int out_size, void* d_ws, size_t ws_size,
                              hipStream_t stream) {
    const float* x     = (const float*)d_in[0];
    const float* Wqkv  = (const float*)d_in[1];
    const float* bqkv  = (const float*)d_in[2];
    const float* Wproj = (const float*)d_in[3];
    const float* bproj = (const float*)d_in[4];
    float* out = (float*)d_out;

    char* ws = (char*)d_ws;
    _Float16* qkvh   = (_Float16*)ws;  ws += (size_t)BTROWS * QKVCOLS * 2;
    _Float16* yh     = (_Float16*)ws;  ws += (size_t)BTROWS * CEMB * 2;
    _Float16* xh     = (_Float16*)ws;  ws += (size_t)BTROWS * CEMB * 2;
    _Float16* Wqkvt  = (_Float16*)ws;  ws += (size_t)QKVCOLS * CEMB * 2;
    _Float16* Wprojt = (_Float16*)ws;

    convert_f16_kernel<<<(BTROWS * CEMB) / (256 * 8), 256, 0, stream>>>(x, xh);
    transpose_f16_kernel<<<(CEMB / 32) * (QKVCOLS / 32), 256, 0, stream>>>(
        Wqkv, Wqkvt, CEMB, QKVCOLS);
    transpose_f16_kernel<<<(CEMB / 32) * (CEMB / 32), 256, 0, stream>>>(
        Wproj, Wprojt, CEMB, CEMB);

    gemm_f16_kernel<_Float16><<<(BTROWS / 128) * (QKVCOLS / 128), 256, 0, stream>>>(
        xh, Wqkvt, bqkv, qkvh, BTROWS, QKVCOLS, CEMB);

    attn_kernel<<<BATCH * NHEAD * (NQT / 2), 256, 0, stream>>>(qkvh, yh);

    gemm_f16_kernel<float><<<(BTROWS / 128) * (CEMB / 128), 256, 0, stream>>>(
        yh, Wprojt, bproj, out, BTROWS, CEMB, CEMB);
}